// Round 5
// baseline (508.474 us; speedup 1.0000x reference)
//
#include <hip/hip_runtime.h>
#include <cstdint>
#include <cstddef>

#define B_ 2
#define S_ 4096
#define T_ 4096
#define D_ 512
#define W_ 128

// degree-4 poly in t=z^2 for h(t) = silu(z) - z/2, fit on t in [0, 6.25]
#define A0C (-0.0006958f)
#define A1C (0.2529946f)
#define A2C (-0.0226345f)
#define A3C (0.0022173f)
#define A4C (-0.00011668f)
#define ZCUT 2.5f

typedef __attribute__((ext_vector_type(8))) short bf16x8;
typedef __attribute__((ext_vector_type(4))) float f32x4;

__device__ __forceinline__ uint16_t f2bf(float f){
  uint32_t u = __float_as_uint(f);
  u += 0x7FFFu + ((u >> 16) & 1u);        // round-to-nearest-even
  return (uint16_t)(u >> 16);
}
__device__ __forceinline__ float bf2f(uint16_t h){
  return __uint_as_float(((uint32_t)h) << 16);
}

__device__ __forceinline__ void gl_lds16(const void* g, void* l){
  __builtin_amdgcn_global_load_lds(
      (const __attribute__((address_space(1))) void*)g,
      (__attribute__((address_space(3))) void*)l, 16, 0, 0);
}

union F4 { float4 v; float f[4]; };

// ---- prep: transpose weights (coalesced WRITES, scattered L2 reads),
//      convert small vecs, cbias, zero maxT.  32 blocks.
template<int INBF>
__global__ void prep_k(const void* __restrict__ Ws, const void* __restrict__ Wt,
                       const void* __restrict__ wso, const void* __restrict__ wto,
                       const void* __restrict__ wi, const void* __restrict__ bias,
                       float* __restrict__ WsT, float* __restrict__ WtT,
                       float* __restrict__ wsof, float* __restrict__ wtof,
                       float* __restrict__ wif, float* __restrict__ cbias,
                       float* __restrict__ maxT){
  auto cv = [](const void* p, int i)->float{
    if (INBF) return bf2f(((const uint16_t*)p)[i]);
    return ((const float*)p)[i];
  };
  const void* in = (blockIdx.x & 1) ? Wt : Ws;
  float* out = (blockIdx.x & 1) ? WtT : WsT;
  int base = (blockIdx.x >> 1) * 4096;
  for (int o = base + threadIdx.x; o < base + 4096; o += blockDim.x){
    int d = o >> 7, w = o & (W_ - 1);
    out[o] = cv(in, w * D_ + d);          // write linear/coalesced
  }
  if (blockIdx.x == 1){
    maxT[threadIdx.x] = 0.f;              // B_*W_ = 256 entries
  }
  if (blockIdx.x == 0){
    if (threadIdx.x < W_){
      wsof[threadIdx.x] = cv(wso, threadIdx.x);
      wtof[threadIdx.x] = cv(wto, threadIdx.x);
      wif[threadIdx.x]  = cv(wi,  threadIdx.x);
    }
    __syncthreads();
    if (threadIdx.x == 0){
      float s = 0.f;
      for (int k = 0; k < W_; ++k) s += wif[k];
      cbias[0] = cv(bias, 0) + A0C * s;
    }
  }
}

// ---- fused projection: raw input -> pT (transposed), lin, bf16 features
// 16 rows/block (512 blocks, 2 waves/SIMD).  MODE 0 = source (features
// scaled by w_int + poly coeffs), MODE 1 = target (+ fused maxT atomicMax)
template<int INBF, int MODE>
__global__ __launch_bounds__(256) void proj_k(const void* __restrict__ xraw,
        const float* __restrict__ WT, const float* __restrict__ wout,
        const float* __restrict__ wint,
        float* __restrict__ pT, float* __restrict__ lin,
        uint16_t* __restrict__ feat, float* __restrict__ maxT){
  __shared__ float xl[64 * 18];
  __shared__ float wl[64 * 128];
  int tid = threadIdx.x;
  int tx = tid & 31, ty = tid >> 5;
  int rowBase = blockIdx.x * 16;
  float acc[2][4] = {};
  for (int c = 0; c < 8; ++c){
    int d0 = c * 64;
    const float4* wt4 = (const float4*)(WT + (size_t)d0 * W_);
    float4* wl4 = (float4*)wl;
    #pragma unroll
    for (int p = 0; p < 8; ++p){ int q = tid + 256 * p; wl4[q] = wt4[q]; }
    {
      int q = tid;
      int r = q >> 4, dq = q & 15;
      float v0, v1, v2, v3;
      if (INBF){
        const uint16_t* xp = (const uint16_t*)xraw + (size_t)(rowBase + r) * D_ + d0 + dq * 4;
        ushort4 u = *(const ushort4*)xp;
        v0 = bf2f(u.x); v1 = bf2f(u.y); v2 = bf2f(u.z); v3 = bf2f(u.w);
      } else {
        const float* xp = (const float*)xraw + (size_t)(rowBase + r) * D_ + d0 + dq * 4;
        float4 u = *(const float4*)xp;
        v0 = u.x; v1 = u.y; v2 = u.z; v3 = u.w;
      }
      xl[(dq*4+0)*18 + r] = v0;
      xl[(dq*4+1)*18 + r] = v1;
      xl[(dq*4+2)*18 + r] = v2;
      xl[(dq*4+3)*18 + r] = v3;
    }
    __syncthreads();
    #pragma unroll 4
    for (int d = 0; d < 64; ++d){
      float a0 = xl[d * 18 + ty * 2 + 0];
      float a1 = xl[d * 18 + ty * 2 + 1];
      F4 w;
      w.v = *(const float4*)(wl + d * 128 + tx * 4);
      #pragma unroll
      for (int j = 0; j < 4; ++j){
        acc[0][j] = fmaf(a0, w.f[j], acc[0][j]);
        acc[1][j] = fmaf(a1, w.f[j], acc[1][j]);
      }
    }
    __syncthreads();
  }
  // stage acc into wl (free after last sync) as [w][r] for transposed write
  float* tile = wl;
  #pragma unroll
  for (int i = 0; i < 2; ++i)
    #pragma unroll
    for (int j = 0; j < 4; ++j)
      tile[(tx*4 + j) * 17 + ty*2 + i] = acc[i][j];
  // register-only work while tile settles: lin + bf16 features
  F4 wo; wo.v = *(const float4*)(wout + tx * 4);
  F4 wiv;
  if (MODE == 0) wiv.v = *(const float4*)(wint + tx * 4);
  #pragma unroll
  for (int i = 0; i < 2; ++i){
    int r = rowBase + ty * 2 + i;
    float s = acc[i][0]*wo.f[0] + acc[i][1]*wo.f[1] + acc[i][2]*wo.f[2] + acc[i][3]*wo.f[3];
    #pragma unroll
    for (int off = 16; off >= 1; off >>= 1) s += __shfl_xor(s, off, 32);
    if (tx == 0) lin[r] = s;
    ushort4 g[5];
    uint16_t* gp = (uint16_t*)g;
    #pragma unroll
    for (int j = 0; j < 4; ++j){
      float p = acc[i][j];
      float p2 = p*p, p4 = p2*p2, p6 = p4*p2, p8 = p4*p4;
      float e0, e1, e2, e3, e4;
      if (MODE == 0){
        float wq = wiv.f[j];
        e0 = 0.5f * wq * p; e1 = A1C * wq * p2; e2 = A2C * wq * p4;
        e3 = A3C * wq * p6; e4 = A4C * wq * p8;
      } else {
        e0 = p; e1 = p2; e2 = p4; e3 = p6; e4 = p8;
      }
      gp[0*4+j] = f2bf(e0); gp[1*4+j] = f2bf(e1); gp[2*4+j] = f2bf(e2);
      gp[3*4+j] = f2bf(e3); gp[4*4+j] = f2bf(e4);
    }
    uint16_t* o = feat + (size_t)r * 640 + tx * 4;
    *(ushort4*)(o)       = g[0];
    *(ushort4*)(o + 128) = g[1];
    *(ushort4*)(o + 256) = g[2];
    *(ushort4*)(o + 384) = g[3];
    *(ushort4*)(o + 512) = g[4];
  }
  __syncthreads();
  int b = rowBase >> 12;
  // transposed write: pT[(b*W + w)][s]; scalar LDS reads (stride-17 rows are
  // only 4B-aligned — a float4 LDS read here would be misaligned UB)
  {
    int w = tid >> 1, h = tid & 1;
    int sb = rowBase & (S_ - 1);
    float* dst = pT + ((size_t)(b * W_ + w)) * S_ + sb + h * 8;
    const float* src = tile + w * 17 + h * 8;
    #pragma unroll
    for (int k = 0; k < 2; ++k){
      float4 o = make_float4(src[k*4+0], src[k*4+1], src[k*4+2], src[k*4+3]);
      *(float4*)(dst + k * 4) = o;
    }
  }
  // fused per-(b,w) running max |pt| (fp32 bits monotone for non-negatives)
  if (MODE == 1 && tid < W_){
    int w = tid;
    float m = 0.f;
    #pragma unroll
    for (int r = 0; r < 16; ++r) m = fmaxf(m, fabsf(tile[w * 17 + r]));
    atomicMax((unsigned int*)&maxT[b * W_ + w], __float_as_uint(m));
  }
}

// ---- main GEMM: 128x128 tile, 4 waves, swapped-operand MFMA, K=640 ------
// 2-phase prefetch double-buffer (T3-minimum): issue tile t+1 loads before
// computing tile t; counted s_waitcnt vmcnt(4) keeps prefetch in flight
// across the MFMA phase (never drain to 0 in the main loop).
template<int OUTBF>
__global__ __launch_bounds__(256) void gemm_k(const uint16_t* __restrict__ fA,
      const uint16_t* __restrict__ fB, const float* __restrict__ slin,
      const float* __restrict__ tlin, const float* __restrict__ cbias,
      void* __restrict__ outv){
  __shared__ __align__(16) uint16_t As[2][128 * 32];
  __shared__ __align__(16) uint16_t Bs[2][128 * 32];
  int tid = threadIdx.x, lane = tid & 63, wv = tid >> 6;
  int quad = lane >> 4, lr = lane & 15;
  int rowT = blockIdx.y * 128, colT = blockIdx.x * 128;
  int b = rowT >> 12;
  int r0 = lane >> 2, c0 = (lane & 3) * 8;
  int mBase = (wv & 1) * 64, nBase = (wv >> 1) * 64;

  f32x4 acc[4][4];
  #pragma unroll
  for (int i = 0; i < 4; ++i)
    #pragma unroll
    for (int j = 0; j < 4; ++j)
      acc[i][j] = (f32x4){0.f, 0.f, 0.f, 0.f};

  const uint16_t* aBase = fA + (size_t)rowT * 640;
  const uint16_t* bBase = fB + ((size_t)b * T_ + colT) * 640;

  const int NSTEP = 20;
  // prologue: stage tile 0 into buffer 0
  #pragma unroll
  for (int h = 0; h < 2; ++h){
    int q = 2 * wv + h;
    gl_lds16(aBase + (size_t)(16 * q + r0) * 640 + c0, &As[0][q * 512]);
    gl_lds16(bBase + (size_t)(16 * q + r0) * 640 + c0, &Bs[0][q * 512]);
  }
  for (int step = 0; step < NSTEP; ++step){
    int cur = step & 1;
    if (step + 1 < NSTEP){
      int kc = (step + 1) * 32;
      #pragma unroll
      for (int h = 0; h < 2; ++h){
        int q = 2 * wv + h;
        gl_lds16(aBase + (size_t)(16 * q + r0) * 640 + kc + c0, &As[cur ^ 1][q * 512]);
        gl_lds16(bBase + (size_t)(16 * q + r0) * 640 + kc + c0, &Bs[cur ^ 1][q * 512]);
      }
      // wait for current tile's 4 loads (oldest); leave next tile's 4 in flight
      asm volatile("s_waitcnt vmcnt(4)" ::: "memory");
    } else {
      asm volatile("s_waitcnt vmcnt(0)" ::: "memory");
    }
    __builtin_amdgcn_s_barrier();
    bf16x8 af[4], bfr[4];
    #pragma unroll
    for (int i = 0; i < 4; ++i)
      af[i] = *(const bf16x8*)&As[cur][(mBase + i * 16 + lr) * 32 + quad * 8];
    #pragma unroll
    for (int j = 0; j < 4; ++j)
      bfr[j] = *(const bf16x8*)&Bs[cur][(nBase + j * 16 + lr) * 32 + quad * 8];
    // swapped operands: lane holds s-row = lr (fixed), t-cols = quad*4+reg
    #pragma unroll
    for (int i = 0; i < 4; ++i)
      #pragma unroll
      for (int j = 0; j < 4; ++j)
        acc[i][j] = __builtin_amdgcn_mfma_f32_16x16x32_bf16(bfr[j], af[i], acc[i][j], 0, 0, 0);
    __builtin_amdgcn_s_barrier();
  }

  float cb = cbias[0];
  #pragma unroll
  for (int i = 0; i < 4; ++i){
    int srow = rowT + mBase + i * 16 + lr;
    float sl = slin[srow] + cb;
    #pragma unroll
    for (int j = 0; j < 4; ++j){
      int t0 = colT + nBase + j * 16 + quad * 4;
      F4 tl; tl.v = *(const float4*)(tlin + b * T_ + t0);
      float o0 = acc[i][j][0] + sl + tl.f[0];
      float o1 = acc[i][j][1] + sl + tl.f[1];
      float o2 = acc[i][j][2] + sl + tl.f[2];
      float o3 = acc[i][j][3] + sl + tl.f[3];
      size_t oi = (size_t)srow * T_ + t0;
      if (OUTBF){
        ushort4 pk = make_ushort4(f2bf(o0), f2bf(o1), f2bf(o2), f2bf(o3));
        *(ushort4*)((uint16_t*)outv + oi) = pk;
      } else {
        *(float4*)((float*)outv + oi) = make_float4(o0, o1, o2, o3);
      }
    }
  }
}

// ---- merged flag+fix: one block per (w,b); flag s into LDS list, then
//      block-wide exact fix merged into d_out --------------------------
template<int OUTBF>
__global__ __launch_bounds__(256) void flagfix_k(const float* __restrict__ psT,
        const float* __restrict__ ptT, const float* __restrict__ wint,
        const uint16_t* __restrict__ fA, const uint16_t* __restrict__ fB,
        const float* __restrict__ maxT, void* __restrict__ outv){
  __shared__ int cnt;
  __shared__ uint16_t list[S_];
  int w = blockIdx.x, b = blockIdx.y;
  int tid = threadIdx.x;
  if (tid == 0) cnt = 0;
  __syncthreads();
  float mt = maxT[b * W_ + w];
  const float* psc = psT + (size_t)(b * W_ + w) * S_;
  for (int s = tid; s < S_; s += 256){
    if (fabsf(psc[s]) * mt > ZCUT){
      int k = atomicAdd(&cnt, 1);
      list[k] = (uint16_t)s;
    }
  }
  __syncthreads();
  int n = cnt;
  if (n == 0) return;
  float wi = wint[w];
  const float* ptc = ptT + (size_t)(b * W_ + w) * T_;
  for (int ji = 0; ji < n; ++ji){
    int s = (int)list[ji];
    float p = psc[s];
    const uint16_t* fa = fA + ((size_t)b * S_ + s) * 640 + w;
    float a0 = bf2f(fa[0]),   a1 = bf2f(fa[128]), a2 = bf2f(fa[256]);
    float a3 = bf2f(fa[384]), a4 = bf2f(fa[512]);
    for (int t = tid; t < T_; t += 256){
      float q = ptc[t];
      float z = p * q;
      if (fabsf(z) > ZCUT){
        const uint16_t* fb = fB + ((size_t)b * T_ + t) * 640 + w;
        float dot = a0 * bf2f(fb[0]) + a1 * bf2f(fb[128]) + a2 * bf2f(fb[256])
                  + a3 * bf2f(fb[384]) + a4 * bf2f(fb[512]);
        float sil = z / (1.0f + __expf(-z));
        float corr = wi * sil - dot - A0C * wi;
        size_t idx = ((size_t)b * S_ + s) * T_ + t;
        if (OUTBF){
          uint32_t* wp = (uint32_t*)outv + (idx >> 1);
          bool hi = (idx & 1u) != 0;
          uint32_t assumed, old = *wp;
          do {
            assumed = old;
            uint16_t h = hi ? (uint16_t)(assumed >> 16) : (uint16_t)(assumed & 0xFFFFu);
            uint16_t nh = f2bf(bf2f(h) + corr);
            uint32_t nw = hi ? ((assumed & 0x0000FFFFu) | ((uint32_t)nh << 16))
                             : ((assumed & 0xFFFF0000u) | (uint32_t)nh);
            old = atomicCAS(wp, assumed, nw);
          } while (old != assumed);
        } else {
          atomicAdd((float*)outv + idx, corr);
        }
      }
    }
  }
}

extern "C" void kernel_launch(void* const* d_in, const int* in_sizes, int n_in,
                              void* d_out, int out_size, void* d_ws, size_t ws_size,
                              hipStream_t stream){
  char* ws = (char*)d_ws;
  size_t off = 0;
  auto alloc = [&](size_t bytes)->char*{
    char* p = ws + off; off += (bytes + 255) & ~(size_t)255; return p;
  };
  float*    WsT  = (float*)   alloc((size_t)D_*W_*4);
  float*    WtT  = (float*)   alloc((size_t)D_*W_*4);
  float*    wsof = (float*)   alloc(W_*4);
  float*    wtof = (float*)   alloc(W_*4);
  float*    wif  = (float*)   alloc(W_*4);
  float*    cbias= (float*)   alloc(4);
  float*    psT  = (float*)   alloc((size_t)B_*S_*W_*4);
  float*    ptT  = (float*)   alloc((size_t)B_*T_*W_*4);
  float*    slin = (float*)   alloc((size_t)B_*S_*4);
  float*    tlin = (float*)   alloc((size_t)B_*T_*4);
  float*    maxT = (float*)   alloc((size_t)B_*W_*4);
  uint16_t* featA= (uint16_t*)alloc((size_t)B_*S_*640*2);
  uint16_t* featB= (uint16_t*)alloc((size_t)B_*T_*640*2);

  // host-side dtype dispatch from byte sizes (fp32 if ambiguous)
  bool inbf  = (in_sizes[0] == (int)((size_t)B_*S_*D_*2));
  bool outbf = (out_size    == (int)((size_t)B_*S_*T_*2));

  if (inbf){
    hipLaunchKernelGGL((prep_k<1>), dim3(32), dim3(256), 0, stream,
        d_in[2], d_in[3], d_in[4], d_in[5], d_in[6], d_in[7],
        WsT, WtT, wsof, wtof, wif, cbias, maxT);
    hipLaunchKernelGGL((proj_k<1,0>), dim3(B_*S_/16), dim3(256), 0, stream,
        d_in[0], WsT, wsof, wif, psT, slin, featA, maxT);
    hipLaunchKernelGGL((proj_k<1,1>), dim3(B_*T_/16), dim3(256), 0, stream,
        d_in[1], WtT, wtof, wif, ptT, tlin, featB, maxT);
  } else {
    hipLaunchKernelGGL((prep_k<0>), dim3(32), dim3(256), 0, stream,
        d_in[2], d_in[3], d_in[4], d_in[5], d_in[6], d_in[7],
        WsT, WtT, wsof, wtof, wif, cbias, maxT);
    hipLaunchKernelGGL((proj_k<0,0>), dim3(B_*S_/16), dim3(256), 0, stream,
        d_in[0], WsT, wsof, wif, psT, slin, featA, maxT);
    hipLaunchKernelGGL((proj_k<0,1>), dim3(B_*T_/16), dim3(256), 0, stream,
        d_in[1], WtT, wtof, wif, ptT, tlin, featB, maxT);
  }
  if (outbf)
    hipLaunchKernelGGL((gemm_k<1>), dim3(T_/128, B_*S_/128), dim3(256), 0, stream,
        featA, featB, slin, tlin, cbias, d_out);
  else
    hipLaunchKernelGGL((gemm_k<0>), dim3(T_/128, B_*S_/128), dim3(256), 0, stream,
        featA, featB, slin, tlin, cbias, d_out);
  if (outbf)
    hipLaunchKernelGGL((flagfix_k<1>), dim3(W_, B_), dim3(256), 0, stream,
        psT, ptT, wif, featA, featB, maxT, d_out);
  else
    hipLaunchKernelGGL((flagfix_k<0>), dim3(W_, B_), dim3(256), 0, stream,
        psT, ptT, wif, featA, featB, maxT, d_out);
}

// Round 6
// 305.092 us; speedup vs baseline: 1.6666x; 1.6666x over previous
//
#include <hip/hip_runtime.h>
#include <cstdint>
#include <cstddef>

#define B_ 2
#define S_ 4096
#define T_ 4096
#define D_ 512
#define W_ 128

// degree-4 poly in t=z^2 for h(t) = silu(z) - z/2, fit on t in [0, 6.25]
#define A0C (-0.0006958f)
#define A1C (0.2529946f)
#define A2C (-0.0226345f)
#define A3C (0.0022173f)
#define A4C (-0.00011668f)
#define ZCUT 2.5f
#define ROWCAP 65536

typedef __attribute__((ext_vector_type(8))) short bf16x8;
typedef __attribute__((ext_vector_type(4))) float f32x4;

__device__ __forceinline__ uint16_t f2bf(float f){
  uint32_t u = __float_as_uint(f);
  u += 0x7FFFu + ((u >> 16) & 1u);        // round-to-nearest-even
  return (uint16_t)(u >> 16);
}
__device__ __forceinline__ float bf2f(uint16_t h){
  return __uint_as_float(((uint32_t)h) << 16);
}

__device__ __forceinline__ void gl_lds16(const void* g, void* l){
  __builtin_amdgcn_global_load_lds(
      (const __attribute__((address_space(1))) void*)g,
      (__attribute__((address_space(3))) void*)l, 16, 0, 0);
}

union F4 { float4 v; float f[4]; };

// ---- prep: transpose weights (coalesced WRITES, scattered L2 reads),
//      convert small vecs, cbias, zero maxT + rowCnt.  32 blocks.
template<int INBF>
__global__ void prep_k(const void* __restrict__ Ws, const void* __restrict__ Wt,
                       const void* __restrict__ wso, const void* __restrict__ wto,
                       const void* __restrict__ wi, const void* __restrict__ bias,
                       float* __restrict__ WsT, float* __restrict__ WtT,
                       float* __restrict__ wsof, float* __restrict__ wtof,
                       float* __restrict__ wif, float* __restrict__ cbias,
                       float* __restrict__ maxT, int* __restrict__ rowCnt){
  auto cv = [](const void* p, int i)->float{
    if (INBF) return bf2f(((const uint16_t*)p)[i]);
    return ((const float*)p)[i];
  };
  const void* in = (blockIdx.x & 1) ? Wt : Ws;
  float* out = (blockIdx.x & 1) ? WtT : WsT;
  int base = (blockIdx.x >> 1) * 4096;
  for (int o = base + threadIdx.x; o < base + 4096; o += blockDim.x){
    int d = o >> 7, w = o & (W_ - 1);
    out[o] = cv(in, w * D_ + d);          // write linear/coalesced
  }
  if (blockIdx.x == 1){
    maxT[threadIdx.x] = 0.f;              // B_*W_ = 256 entries
  }
  if (blockIdx.x == 0){
    if (threadIdx.x < W_){
      wsof[threadIdx.x] = cv(wso, threadIdx.x);
      wtof[threadIdx.x] = cv(wto, threadIdx.x);
      wif[threadIdx.x]  = cv(wi,  threadIdx.x);
    }
    __syncthreads();
    if (threadIdx.x == 0){
      float s = 0.f;
      for (int k = 0; k < W_; ++k) s += wif[k];
      cbias[0] = cv(bias, 0) + A0C * s;
      rowCnt[0] = 0;
    }
  }
}

// ---- fused projection: raw input -> pT (transposed), lin, bf16 features
// 16 rows/block (512 blocks, 2 waves/SIMD).  MODE 0 = source (features
// scaled by w_int + poly coeffs), MODE 1 = target (+ fused maxT atomicMax)
template<int INBF, int MODE>
__global__ __launch_bounds__(256) void proj_k(const void* __restrict__ xraw,
        const float* __restrict__ WT, const float* __restrict__ wout,
        const float* __restrict__ wint,
        float* __restrict__ pT, float* __restrict__ lin,
        uint16_t* __restrict__ feat, float* __restrict__ maxT){
  __shared__ float xl[64 * 18];
  __shared__ float wl[64 * 128];
  int tid = threadIdx.x;
  int tx = tid & 31, ty = tid >> 5;
  int rowBase = blockIdx.x * 16;
  float acc[2][4] = {};
  for (int c = 0; c < 8; ++c){
    int d0 = c * 64;
    const float4* wt4 = (const float4*)(WT + (size_t)d0 * W_);
    float4* wl4 = (float4*)wl;
    #pragma unroll
    for (int p = 0; p < 8; ++p){ int q = tid + 256 * p; wl4[q] = wt4[q]; }
    {
      int q = tid;
      int r = q >> 4, dq = q & 15;
      float v0, v1, v2, v3;
      if (INBF){
        const uint16_t* xp = (const uint16_t*)xraw + (size_t)(rowBase + r) * D_ + d0 + dq * 4;
        ushort4 u = *(const ushort4*)xp;
        v0 = bf2f(u.x); v1 = bf2f(u.y); v2 = bf2f(u.z); v3 = bf2f(u.w);
      } else {
        const float* xp = (const float*)xraw + (size_t)(rowBase + r) * D_ + d0 + dq * 4;
        float4 u = *(const float4*)xp;
        v0 = u.x; v1 = u.y; v2 = u.z; v3 = u.w;
      }
      xl[(dq*4+0)*18 + r] = v0;
      xl[(dq*4+1)*18 + r] = v1;
      xl[(dq*4+2)*18 + r] = v2;
      xl[(dq*4+3)*18 + r] = v3;
    }
    __syncthreads();
    #pragma unroll 4
    for (int d = 0; d < 64; ++d){
      float a0 = xl[d * 18 + ty * 2 + 0];
      float a1 = xl[d * 18 + ty * 2 + 1];
      F4 w;
      w.v = *(const float4*)(wl + d * 128 + tx * 4);
      #pragma unroll
      for (int j = 0; j < 4; ++j){
        acc[0][j] = fmaf(a0, w.f[j], acc[0][j]);
        acc[1][j] = fmaf(a1, w.f[j], acc[1][j]);
      }
    }
    __syncthreads();
  }
  // stage acc into wl (free after last sync) as [w][r] for transposed write
  float* tile = wl;
  #pragma unroll
  for (int i = 0; i < 2; ++i)
    #pragma unroll
    for (int j = 0; j < 4; ++j)
      tile[(tx*4 + j) * 17 + ty*2 + i] = acc[i][j];
  // register-only work while tile settles: lin + bf16 features
  F4 wo; wo.v = *(const float4*)(wout + tx * 4);
  F4 wiv;
  if (MODE == 0) wiv.v = *(const float4*)(wint + tx * 4);
  #pragma unroll
  for (int i = 0; i < 2; ++i){
    int r = rowBase + ty * 2 + i;
    float s = acc[i][0]*wo.f[0] + acc[i][1]*wo.f[1] + acc[i][2]*wo.f[2] + acc[i][3]*wo.f[3];
    #pragma unroll
    for (int off = 16; off >= 1; off >>= 1) s += __shfl_xor(s, off, 32);
    if (tx == 0) lin[r] = s;
    ushort4 g[5];
    uint16_t* gp = (uint16_t*)g;
    #pragma unroll
    for (int j = 0; j < 4; ++j){
      float p = acc[i][j];
      float p2 = p*p, p4 = p2*p2, p6 = p4*p2, p8 = p4*p4;
      float e0, e1, e2, e3, e4;
      if (MODE == 0){
        float wq = wiv.f[j];
        e0 = 0.5f * wq * p; e1 = A1C * wq * p2; e2 = A2C * wq * p4;
        e3 = A3C * wq * p6; e4 = A4C * wq * p8;
      } else {
        e0 = p; e1 = p2; e2 = p4; e3 = p6; e4 = p8;
      }
      gp[0*4+j] = f2bf(e0); gp[1*4+j] = f2bf(e1); gp[2*4+j] = f2bf(e2);
      gp[3*4+j] = f2bf(e3); gp[4*4+j] = f2bf(e4);
    }
    uint16_t* o = feat + (size_t)r * 640 + tx * 4;
    *(ushort4*)(o)       = g[0];
    *(ushort4*)(o + 128) = g[1];
    *(ushort4*)(o + 256) = g[2];
    *(ushort4*)(o + 384) = g[3];
    *(ushort4*)(o + 512) = g[4];
  }
  __syncthreads();
  int b = rowBase >> 12;
  // transposed write: pT[(b*W + w)][s]; scalar LDS reads (stride-17 rows are
  // only 4B-aligned — a float4 LDS read here would be misaligned UB)
  {
    int w = tid >> 1, h = tid & 1;
    int sb = rowBase & (S_ - 1);
    float* dst = pT + ((size_t)(b * W_ + w)) * S_ + sb + h * 8;
    const float* src = tile + w * 17 + h * 8;
    #pragma unroll
    for (int k = 0; k < 2; ++k){
      float4 o = make_float4(src[k*4+0], src[k*4+1], src[k*4+2], src[k*4+3]);
      *(float4*)(dst + k * 4) = o;
    }
  }
  // fused per-(b,w) running max |pt| (fp32 bits monotone for non-negatives)
  if (MODE == 1 && tid < W_){
    int w = tid;
    float m = 0.f;
    #pragma unroll
    for (int r = 0; r < 16; ++r) m = fmaxf(m, fabsf(tile[w * 17 + r]));
    atomicMax((unsigned int*)&maxT[b * W_ + w], __float_as_uint(m));
  }
}

// ---- main GEMM: 128x128 tile, 4 waves, swapped-operand MFMA, K=640 ------
// 2-phase prefetch double-buffer (T3-minimum): issue tile t+1 loads before
// computing tile t; counted s_waitcnt vmcnt(4) keeps prefetch in flight
// across the MFMA phase (never drain to 0 in the main loop).
template<int OUTBF>
__global__ __launch_bounds__(256) void gemm_k(const uint16_t* __restrict__ fA,
      const uint16_t* __restrict__ fB, const float* __restrict__ slin,
      const float* __restrict__ tlin, const float* __restrict__ cbias,
      void* __restrict__ outv){
  __shared__ __align__(16) uint16_t As[2][128 * 32];
  __shared__ __align__(16) uint16_t Bs[2][128 * 32];
  int tid = threadIdx.x, lane = tid & 63, wv = tid >> 6;
  int quad = lane >> 4, lr = lane & 15;
  int rowT = blockIdx.y * 128, colT = blockIdx.x * 128;
  int b = rowT >> 12;
  int r0 = lane >> 2, c0 = (lane & 3) * 8;
  int mBase = (wv & 1) * 64, nBase = (wv >> 1) * 64;

  f32x4 acc[4][4];
  #pragma unroll
  for (int i = 0; i < 4; ++i)
    #pragma unroll
    for (int j = 0; j < 4; ++j)
      acc[i][j] = (f32x4){0.f, 0.f, 0.f, 0.f};

  const uint16_t* aBase = fA + (size_t)rowT * 640;
  const uint16_t* bBase = fB + ((size_t)b * T_ + colT) * 640;

  const int NSTEP = 20;
  // prologue: stage tile 0 into buffer 0
  #pragma unroll
  for (int h = 0; h < 2; ++h){
    int q = 2 * wv + h;
    gl_lds16(aBase + (size_t)(16 * q + r0) * 640 + c0, &As[0][q * 512]);
    gl_lds16(bBase + (size_t)(16 * q + r0) * 640 + c0, &Bs[0][q * 512]);
  }
  for (int step = 0; step < NSTEP; ++step){
    int cur = step & 1;
    if (step + 1 < NSTEP){
      int kc = (step + 1) * 32;
      #pragma unroll
      for (int h = 0; h < 2; ++h){
        int q = 2 * wv + h;
        gl_lds16(aBase + (size_t)(16 * q + r0) * 640 + kc + c0, &As[cur ^ 1][q * 512]);
        gl_lds16(bBase + (size_t)(16 * q + r0) * 640 + kc + c0, &Bs[cur ^ 1][q * 512]);
      }
      // wait for current tile's 4 loads (oldest); leave next tile's 4 in flight
      asm volatile("s_waitcnt vmcnt(4)" ::: "memory");
    } else {
      asm volatile("s_waitcnt vmcnt(0)" ::: "memory");
    }
    __builtin_amdgcn_s_barrier();
    bf16x8 af[4], bfr[4];
    #pragma unroll
    for (int i = 0; i < 4; ++i)
      af[i] = *(const bf16x8*)&As[cur][(mBase + i * 16 + lr) * 32 + quad * 8];
    #pragma unroll
    for (int j = 0; j < 4; ++j)
      bfr[j] = *(const bf16x8*)&Bs[cur][(nBase + j * 16 + lr) * 32 + quad * 8];
    // swapped operands: lane holds s-row = lr (fixed), t-cols = quad*4+reg
    #pragma unroll
    for (int i = 0; i < 4; ++i)
      #pragma unroll
      for (int j = 0; j < 4; ++j)
        acc[i][j] = __builtin_amdgcn_mfma_f32_16x16x32_bf16(bfr[j], af[i], acc[i][j], 0, 0, 0);
    __builtin_amdgcn_s_barrier();
  }

  float cb = cbias[0];
  #pragma unroll
  for (int i = 0; i < 4; ++i){
    int srow = rowT + mBase + i * 16 + lr;
    float sl = slin[srow] + cb;
    #pragma unroll
    for (int j = 0; j < 4; ++j){
      int t0 = colT + nBase + j * 16 + quad * 4;
      F4 tl; tl.v = *(const float4*)(tlin + b * T_ + t0);
      float o0 = acc[i][j][0] + sl + tl.f[0];
      float o1 = acc[i][j][1] + sl + tl.f[1];
      float o2 = acc[i][j][2] + sl + tl.f[2];
      float o3 = acc[i][j][3] + sl + tl.f[3];
      size_t oi = (size_t)srow * T_ + t0;
      if (OUTBF){
        ushort4 pk = make_ushort4(f2bf(o0), f2bf(o1), f2bf(o2), f2bf(o3));
        *(ushort4*)((uint16_t*)outv + oi) = pk;
      } else {
        *(float4*)((float*)outv + oi) = make_float4(o0, o1, o2, o3);
      }
    }
  }
}

// ---- phase 1: flag rows where |ps|*maxT > ZCUT (coalesced, parallel) ----
__global__ void flagrows_k(const float* __restrict__ psT, const float* __restrict__ maxT,
                           uint32_t* __restrict__ rowList, int* __restrict__ rowCnt){
  int w = blockIdx.x, b = blockIdx.y;
  int tid = threadIdx.x;
  float mt = maxT[b * W_ + w];
  const float* psc = psT + (size_t)(b * W_ + w) * S_;
  for (int s = tid; s < S_; s += 256){
    float p = psc[s];
    if (fabsf(p) * mt > ZCUT){
      int k = atomicAdd(rowCnt, 1);
      if (k < ROWCAP)
        rowList[k] = ((uint32_t)b << 19) | ((uint32_t)w << 12) | (uint32_t)s;
    }
  }
}

// ---- phase 2: grid-stride over flagged rows (load-balanced); exact fix
//      merged into d_out ------------------------------------------------
template<int OUTBF>
__global__ __launch_bounds__(256) void fixscan_k(const float* __restrict__ psT,
        const float* __restrict__ ptT, const float* __restrict__ wint,
        const uint16_t* __restrict__ fA, const uint16_t* __restrict__ fB,
        const uint32_t* __restrict__ rowList, const int* __restrict__ rowCnt,
        void* __restrict__ outv){
  int n = *rowCnt; if (n > ROWCAP) n = ROWCAP;
  int tid = threadIdx.x;
  for (int job = blockIdx.x; job < n; job += gridDim.x){
    uint32_t pk = rowList[job];
    int b = (int)(pk >> 19), w = (int)((pk >> 12) & 127u), s = (int)(pk & 4095u);
    float wi = wint[w];
    float p = psT[(size_t)(b * W_ + w) * S_ + s];
    const float* ptc = ptT + (size_t)(b * W_ + w) * T_;
    const uint16_t* fa = fA + ((size_t)b * S_ + s) * 640 + w;
    float a0 = bf2f(fa[0]),   a1 = bf2f(fa[128]), a2 = bf2f(fa[256]);
    float a3 = bf2f(fa[384]), a4 = bf2f(fa[512]);
    for (int t = tid; t < T_; t += 256){
      float q = ptc[t];
      float z = p * q;
      if (fabsf(z) > ZCUT){
        const uint16_t* fb = fB + ((size_t)b * T_ + t) * 640 + w;
        float dot = a0 * bf2f(fb[0]) + a1 * bf2f(fb[128]) + a2 * bf2f(fb[256])
                  + a3 * bf2f(fb[384]) + a4 * bf2f(fb[512]);
        float sil = z / (1.0f + __expf(-z));
        float corr = wi * sil - dot - A0C * wi;
        size_t idx = ((size_t)b * S_ + s) * T_ + t;
        if (OUTBF){
          uint32_t* wp = (uint32_t*)outv + (idx >> 1);
          bool hi = (idx & 1u) != 0;
          uint32_t assumed, old = *wp;
          do {
            assumed = old;
            uint16_t h = hi ? (uint16_t)(assumed >> 16) : (uint16_t)(assumed & 0xFFFFu);
            uint16_t nh = f2bf(bf2f(h) + corr);
            uint32_t nw = hi ? ((assumed & 0x0000FFFFu) | ((uint32_t)nh << 16))
                             : ((assumed & 0xFFFF0000u) | (uint32_t)nh);
            old = atomicCAS(wp, assumed, nw);
          } while (old != assumed);
        } else {
          atomicAdd((float*)outv + idx, corr);
        }
      }
    }
  }
}

extern "C" void kernel_launch(void* const* d_in, const int* in_sizes, int n_in,
                              void* d_out, int out_size, void* d_ws, size_t ws_size,
                              hipStream_t stream){
  char* ws = (char*)d_ws;
  size_t off = 0;
  auto alloc = [&](size_t bytes)->char*{
    char* p = ws + off; off += (bytes + 255) & ~(size_t)255; return p;
  };
  float*    WsT  = (float*)   alloc((size_t)D_*W_*4);
  float*    WtT  = (float*)   alloc((size_t)D_*W_*4);
  float*    wsof = (float*)   alloc(W_*4);
  float*    wtof = (float*)   alloc(W_*4);
  float*    wif  = (float*)   alloc(W_*4);
  float*    cbias= (float*)   alloc(4);
  int*      rowCnt=(int*)     alloc(4);
  uint32_t* rowList=(uint32_t*)alloc((size_t)ROWCAP*4);
  float*    psT  = (float*)   alloc((size_t)B_*S_*W_*4);
  float*    ptT  = (float*)   alloc((size_t)B_*T_*W_*4);
  float*    slin = (float*)   alloc((size_t)B_*S_*4);
  float*    tlin = (float*)   alloc((size_t)B_*T_*4);
  float*    maxT = (float*)   alloc((size_t)B_*W_*4);
  uint16_t* featA= (uint16_t*)alloc((size_t)B_*S_*640*2);
  uint16_t* featB= (uint16_t*)alloc((size_t)B_*T_*640*2);

  // host-side dtype dispatch from byte sizes (fp32 if ambiguous)
  bool inbf  = (in_sizes[0] == (int)((size_t)B_*S_*D_*2));
  bool outbf = (out_size    == (int)((size_t)B_*S_*T_*2));

  if (inbf){
    hipLaunchKernelGGL((prep_k<1>), dim3(32), dim3(256), 0, stream,
        d_in[2], d_in[3], d_in[4], d_in[5], d_in[6], d_in[7],
        WsT, WtT, wsof, wtof, wif, cbias, maxT, rowCnt);
    hipLaunchKernelGGL((proj_k<1,0>), dim3(B_*S_/16), dim3(256), 0, stream,
        d_in[0], WsT, wsof, wif, psT, slin, featA, maxT);
    hipLaunchKernelGGL((proj_k<1,1>), dim3(B_*T_/16), dim3(256), 0, stream,
        d_in[1], WtT, wtof, wif, ptT, tlin, featB, maxT);
  } else {
    hipLaunchKernelGGL((prep_k<0>), dim3(32), dim3(256), 0, stream,
        d_in[2], d_in[3], d_in[4], d_in[5], d_in[6], d_in[7],
        WsT, WtT, wsof, wtof, wif, cbias, maxT, rowCnt);
    hipLaunchKernelGGL((proj_k<0,0>), dim3(B_*S_/16), dim3(256), 0, stream,
        d_in[0], WsT, wsof, wif, psT, slin, featA, maxT);
    hipLaunchKernelGGL((proj_k<0,1>), dim3(B_*T_/16), dim3(256), 0, stream,
        d_in[1], WtT, wtof, wif, ptT, tlin, featB, maxT);
  }
  if (outbf)
    hipLaunchKernelGGL((gemm_k<1>), dim3(T_/128, B_*S_/128), dim3(256), 0, stream,
        featA, featB, slin, tlin, cbias, d_out);
  else
    hipLaunchKernelGGL((gemm_k<0>), dim3(T_/128, B_*S_/128), dim3(256), 0, stream,
        featA, featB, slin, tlin, cbias, d_out);
  hipLaunchKernelGGL(flagrows_k, dim3(W_, B_), dim3(256), 0, stream,
      psT, maxT, rowList, rowCnt);
  if (outbf)
    hipLaunchKernelGGL((fixscan_k<1>), dim3(2048), dim3(256), 0, stream,
        psT, ptT, wif, featA, featB, rowList, rowCnt, d_out);
  else
    hipLaunchKernelGGL((fixscan_k<0>), dim3(2048), dim3(256), 0, stream,
        psT, ptT, wif, featA, featB, rowList, rowCnt, d_out);
}

// Round 7
// 303.102 us; speedup vs baseline: 1.6776x; 1.0066x over previous
//
#include <hip/hip_runtime.h>
#include <cstdint>
#include <cstddef>

#define B_ 2
#define S_ 4096
#define T_ 4096
#define D_ 512
#define W_ 128

// degree-4 poly in t=z^2 for h(t) = silu(z) - z/2, fit on t in [0, 6.25]
#define A0C (-0.0006958f)
#define A1C (0.2529946f)
#define A2C (-0.0226345f)
#define A3C (0.0022173f)
#define A4C (-0.00011668f)
#define ZCUT 2.5f
#define ROWCAP 65536

typedef __attribute__((ext_vector_type(8))) short bf16x8;
typedef __attribute__((ext_vector_type(4))) float f32x4;

__device__ __forceinline__ uint16_t f2bf(float f){
  uint32_t u = __float_as_uint(f);
  u += 0x7FFFu + ((u >> 16) & 1u);        // round-to-nearest-even
  return (uint16_t)(u >> 16);
}
__device__ __forceinline__ float bf2f(uint16_t h){
  return __uint_as_float(((uint32_t)h) << 16);
}

__device__ __forceinline__ void gl_lds16(const void* g, void* l){
  __builtin_amdgcn_global_load_lds(
      (const __attribute__((address_space(1))) void*)g,
      (__attribute__((address_space(3))) void*)l, 16, 0, 0);
}

union F4 { float4 v; float f[4]; };

// ---- prep: transpose weights (coalesced WRITES, scattered L2 reads),
//      convert small vecs, cbias, zero maxT + rowCnt.  32 blocks.
template<int INBF>
__global__ void prep_k(const void* __restrict__ Ws, const void* __restrict__ Wt,
                       const void* __restrict__ wso, const void* __restrict__ wto,
                       const void* __restrict__ wi, const void* __restrict__ bias,
                       float* __restrict__ WsT, float* __restrict__ WtT,
                       float* __restrict__ wsof, float* __restrict__ wtof,
                       float* __restrict__ wif, float* __restrict__ cbias,
                       float* __restrict__ maxT, int* __restrict__ rowCnt){
  auto cv = [](const void* p, int i)->float{
    if (INBF) return bf2f(((const uint16_t*)p)[i]);
    return ((const float*)p)[i];
  };
  const void* in = (blockIdx.x & 1) ? Wt : Ws;
  float* out = (blockIdx.x & 1) ? WtT : WsT;
  int base = (blockIdx.x >> 1) * 4096;
  for (int o = base + threadIdx.x; o < base + 4096; o += blockDim.x){
    int d = o >> 7, w = o & (W_ - 1);
    out[o] = cv(in, w * D_ + d);          // write linear/coalesced
  }
  if (blockIdx.x == 1){
    maxT[threadIdx.x] = 0.f;              // B_*W_ = 256 entries
  }
  if (blockIdx.x == 0){
    if (threadIdx.x < W_){
      wsof[threadIdx.x] = cv(wso, threadIdx.x);
      wtof[threadIdx.x] = cv(wto, threadIdx.x);
      wif[threadIdx.x]  = cv(wi,  threadIdx.x);
    }
    __syncthreads();
    if (threadIdx.x == 0){
      float s = 0.f;
      for (int k = 0; k < W_; ++k) s += wif[k];
      cbias[0] = cv(bias, 0) + A0C * s;
      rowCnt[0] = 0;
    }
  }
}

// ---- fused projection: raw input -> pT (transposed), lin, bf16 features
// 16 rows/block (512 blocks, 2 waves/SIMD).  MODE 0 = source (features
// scaled by w_int + poly coeffs), MODE 1 = target (+ fused maxT atomicMax)
template<int INBF, int MODE>
__global__ __launch_bounds__(256) void proj_k(const void* __restrict__ xraw,
        const float* __restrict__ WT, const float* __restrict__ wout,
        const float* __restrict__ wint,
        float* __restrict__ pT, float* __restrict__ lin,
        uint16_t* __restrict__ feat, float* __restrict__ maxT){
  __shared__ float xl[64 * 18];
  __shared__ float wl[64 * 128];
  int tid = threadIdx.x;
  int tx = tid & 31, ty = tid >> 5;
  int rowBase = blockIdx.x * 16;
  float acc[2][4] = {};
  for (int c = 0; c < 8; ++c){
    int d0 = c * 64;
    const float4* wt4 = (const float4*)(WT + (size_t)d0 * W_);
    float4* wl4 = (float4*)wl;
    #pragma unroll
    for (int p = 0; p < 8; ++p){ int q = tid + 256 * p; wl4[q] = wt4[q]; }
    {
      int q = tid;
      int r = q >> 4, dq = q & 15;
      float v0, v1, v2, v3;
      if (INBF){
        const uint16_t* xp = (const uint16_t*)xraw + (size_t)(rowBase + r) * D_ + d0 + dq * 4;
        ushort4 u = *(const ushort4*)xp;
        v0 = bf2f(u.x); v1 = bf2f(u.y); v2 = bf2f(u.z); v3 = bf2f(u.w);
      } else {
        const float* xp = (const float*)xraw + (size_t)(rowBase + r) * D_ + d0 + dq * 4;
        float4 u = *(const float4*)xp;
        v0 = u.x; v1 = u.y; v2 = u.z; v3 = u.w;
      }
      xl[(dq*4+0)*18 + r] = v0;
      xl[(dq*4+1)*18 + r] = v1;
      xl[(dq*4+2)*18 + r] = v2;
      xl[(dq*4+3)*18 + r] = v3;
    }
    __syncthreads();
    #pragma unroll 4
    for (int d = 0; d < 64; ++d){
      float a0 = xl[d * 18 + ty * 2 + 0];
      float a1 = xl[d * 18 + ty * 2 + 1];
      F4 w;
      w.v = *(const float4*)(wl + d * 128 + tx * 4);
      #pragma unroll
      for (int j = 0; j < 4; ++j){
        acc[0][j] = fmaf(a0, w.f[j], acc[0][j]);
        acc[1][j] = fmaf(a1, w.f[j], acc[1][j]);
      }
    }
    __syncthreads();
  }
  // stage acc into wl (free after last sync) as [w][r] for transposed write
  float* tile = wl;
  #pragma unroll
  for (int i = 0; i < 2; ++i)
    #pragma unroll
    for (int j = 0; j < 4; ++j)
      tile[(tx*4 + j) * 17 + ty*2 + i] = acc[i][j];
  // register-only work while tile settles: lin + bf16 features
  F4 wo; wo.v = *(const float4*)(wout + tx * 4);
  F4 wiv;
  if (MODE == 0) wiv.v = *(const float4*)(wint + tx * 4);
  #pragma unroll
  for (int i = 0; i < 2; ++i){
    int r = rowBase + ty * 2 + i;
    float s = acc[i][0]*wo.f[0] + acc[i][1]*wo.f[1] + acc[i][2]*wo.f[2] + acc[i][3]*wo.f[3];
    #pragma unroll
    for (int off = 16; off >= 1; off >>= 1) s += __shfl_xor(s, off, 32);
    if (tx == 0) lin[r] = s;
    ushort4 g[5];
    uint16_t* gp = (uint16_t*)g;
    #pragma unroll
    for (int j = 0; j < 4; ++j){
      float p = acc[i][j];
      float p2 = p*p, p4 = p2*p2, p6 = p4*p2, p8 = p4*p4;
      float e0, e1, e2, e3, e4;
      if (MODE == 0){
        float wq = wiv.f[j];
        e0 = 0.5f * wq * p; e1 = A1C * wq * p2; e2 = A2C * wq * p4;
        e3 = A3C * wq * p6; e4 = A4C * wq * p8;
      } else {
        e0 = p; e1 = p2; e2 = p4; e3 = p6; e4 = p8;
      }
      gp[0*4+j] = f2bf(e0); gp[1*4+j] = f2bf(e1); gp[2*4+j] = f2bf(e2);
      gp[3*4+j] = f2bf(e3); gp[4*4+j] = f2bf(e4);
    }
    uint16_t* o = feat + (size_t)r * 640 + tx * 4;
    *(ushort4*)(o)       = g[0];
    *(ushort4*)(o + 128) = g[1];
    *(ushort4*)(o + 256) = g[2];
    *(ushort4*)(o + 384) = g[3];
    *(ushort4*)(o + 512) = g[4];
  }
  __syncthreads();
  int b = rowBase >> 12;
  // transposed write: pT[(b*W + w)][s]; scalar LDS reads (stride-17 rows are
  // only 4B-aligned — a float4 LDS read here would be misaligned UB)
  {
    int w = tid >> 1, h = tid & 1;
    int sb = rowBase & (S_ - 1);
    float* dst = pT + ((size_t)(b * W_ + w)) * S_ + sb + h * 8;
    const float* src = tile + w * 17 + h * 8;
    #pragma unroll
    for (int k = 0; k < 2; ++k){
      float4 o = make_float4(src[k*4+0], src[k*4+1], src[k*4+2], src[k*4+3]);
      *(float4*)(dst + k * 4) = o;
    }
  }
  // fused per-(b,w) running max |pt| (fp32 bits monotone for non-negatives)
  if (MODE == 1 && tid < W_){
    int w = tid;
    float m = 0.f;
    #pragma unroll
    for (int r = 0; r < 16; ++r) m = fmaxf(m, fabsf(tile[w * 17 + r]));
    atomicMax((unsigned int*)&maxT[b * W_ + w], __float_as_uint(m));
  }
}

// ---- main GEMM: 128x128 tile, 4 waves, swapped-operand MFMA, K=640 ------
// 2-phase prefetch double-buffer + counted vmcnt(4).
// LDS bank-conflict fix (rule #21 both-sides): global SOURCE k-slot is
// pre-permuted by XOR ((lane>>3)&3) so the linear global_load_lds dest
// lands swizzled; the ds_read applies the same XOR (quad ^ (lane>>1)&3).
// Rows r=0..7 then cover all 8 bank-sets (2 lanes/bank = free, was 4-way).
template<int OUTBF>
__global__ __launch_bounds__(256) void gemm_k(const uint16_t* __restrict__ fA,
      const uint16_t* __restrict__ fB, const float* __restrict__ slin,
      const float* __restrict__ tlin, const float* __restrict__ cbias,
      void* __restrict__ outv){
  __shared__ __align__(16) uint16_t As[2][128 * 32];
  __shared__ __align__(16) uint16_t Bs[2][128 * 32];
  int tid = threadIdx.x, lane = tid & 63, wv = tid >> 6;
  int quad = lane >> 4, lr = lane & 15;
  int rowT = blockIdx.y * 128, colT = blockIdx.x * 128;
  int b = rowT >> 12;
  int r0 = lane >> 2;
  int c0 = (((lane & 3) ^ ((lane >> 3) & 3))) * 8;   // pre-swizzled source k-slot
  int xr = (lane >> 1) & 3;                          // read-side XOR (lane-const)
  int mBase = (wv & 1) * 64, nBase = (wv >> 1) * 64;

  f32x4 acc[4][4];
  #pragma unroll
  for (int i = 0; i < 4; ++i)
    #pragma unroll
    for (int j = 0; j < 4; ++j)
      acc[i][j] = (f32x4){0.f, 0.f, 0.f, 0.f};

  const uint16_t* aBase = fA + (size_t)rowT * 640;
  const uint16_t* bBase = fB + ((size_t)b * T_ + colT) * 640;

  const int NSTEP = 20;
  // prologue: stage tile 0 into buffer 0
  #pragma unroll
  for (int h = 0; h < 2; ++h){
    int q = 2 * wv + h;
    gl_lds16(aBase + (size_t)(16 * q + r0) * 640 + c0, &As[0][q * 512]);
    gl_lds16(bBase + (size_t)(16 * q + r0) * 640 + c0, &Bs[0][q * 512]);
  }
  for (int step = 0; step < NSTEP; ++step){
    int cur = step & 1;
    if (step + 1 < NSTEP){
      int kc = (step + 1) * 32;
      #pragma unroll
      for (int h = 0; h < 2; ++h){
        int q = 2 * wv + h;
        gl_lds16(aBase + (size_t)(16 * q + r0) * 640 + kc + c0, &As[cur ^ 1][q * 512]);
        gl_lds16(bBase + (size_t)(16 * q + r0) * 640 + kc + c0, &Bs[cur ^ 1][q * 512]);
      }
      // wait for current tile's 4 loads (oldest); leave next tile's 4 in flight
      asm volatile("s_waitcnt vmcnt(4)" ::: "memory");
    } else {
      asm volatile("s_waitcnt vmcnt(0)" ::: "memory");
    }
    __builtin_amdgcn_s_barrier();
    bf16x8 af[4], bfr[4];
    #pragma unroll
    for (int i = 0; i < 4; ++i)
      af[i] = *(const bf16x8*)&As[cur][(mBase + i * 16 + lr) * 32 + (quad ^ xr) * 8];
    #pragma unroll
    for (int j = 0; j < 4; ++j)
      bfr[j] = *(const bf16x8*)&Bs[cur][(nBase + j * 16 + lr) * 32 + (quad ^ xr) * 8];
    // swapped operands: lane holds s-row = lr (fixed), t-cols = quad*4+reg
    #pragma unroll
    for (int i = 0; i < 4; ++i)
      #pragma unroll
      for (int j = 0; j < 4; ++j)
        acc[i][j] = __builtin_amdgcn_mfma_f32_16x16x32_bf16(bfr[j], af[i], acc[i][j], 0, 0, 0);
    __builtin_amdgcn_s_barrier();
  }

  float cb = cbias[0];
  #pragma unroll
  for (int i = 0; i < 4; ++i){
    int srow = rowT + mBase + i * 16 + lr;
    float sl = slin[srow] + cb;
    #pragma unroll
    for (int j = 0; j < 4; ++j){
      int t0 = colT + nBase + j * 16 + quad * 4;
      F4 tl; tl.v = *(const float4*)(tlin + b * T_ + t0);
      float o0 = acc[i][j][0] + sl + tl.f[0];
      float o1 = acc[i][j][1] + sl + tl.f[1];
      float o2 = acc[i][j][2] + sl + tl.f[2];
      float o3 = acc[i][j][3] + sl + tl.f[3];
      size_t oi = (size_t)srow * T_ + t0;
      if (OUTBF){
        ushort4 pk = make_ushort4(f2bf(o0), f2bf(o1), f2bf(o2), f2bf(o3));
        *(ushort4*)((uint16_t*)outv + oi) = pk;
      } else {
        *(float4*)((float*)outv + oi) = make_float4(o0, o1, o2, o3);
      }
    }
  }
}

// ---- phase 1: flag rows where |ps|*maxT > ZCUT (coalesced, parallel) ----
__global__ void flagrows_k(const float* __restrict__ psT, const float* __restrict__ maxT,
                           uint32_t* __restrict__ rowList, int* __restrict__ rowCnt){
  int w = blockIdx.x, b = blockIdx.y;
  int tid = threadIdx.x;
  float mt = maxT[b * W_ + w];
  const float* psc = psT + (size_t)(b * W_ + w) * S_;
  for (int s = tid; s < S_; s += 256){
    float p = psc[s];
    if (fabsf(p) * mt > ZCUT){
      int k = atomicAdd(rowCnt, 1);
      if (k < ROWCAP)
        rowList[k] = ((uint32_t)b << 19) | ((uint32_t)w << 12) | (uint32_t)s;
    }
  }
}

// ---- phase 2: grid-stride over flagged rows (load-balanced); exact fix
//      merged into d_out ------------------------------------------------
template<int OUTBF>
__global__ __launch_bounds__(256) void fixscan_k(const float* __restrict__ psT,
        const float* __restrict__ ptT, const float* __restrict__ wint,
        const uint16_t* __restrict__ fA, const uint16_t* __restrict__ fB,
        const uint32_t* __restrict__ rowList, const int* __restrict__ rowCnt,
        void* __restrict__ outv){
  int n = *rowCnt; if (n > ROWCAP) n = ROWCAP;
  int tid = threadIdx.x;
  for (int job = blockIdx.x; job < n; job += gridDim.x){
    uint32_t pk = rowList[job];
    int b = (int)(pk >> 19), w = (int)((pk >> 12) & 127u), s = (int)(pk & 4095u);
    float wi = wint[w];
    float p = psT[(size_t)(b * W_ + w) * S_ + s];
    const float* ptc = ptT + (size_t)(b * W_ + w) * T_;
    const uint16_t* fa = fA + ((size_t)b * S_ + s) * 640 + w;
    float a0 = bf2f(fa[0]),   a1 = bf2f(fa[128]), a2 = bf2f(fa[256]);
    float a3 = bf2f(fa[384]), a4 = bf2f(fa[512]);
    for (int t = tid; t < T_; t += 256){
      float q = ptc[t];
      float z = p * q;
      if (fabsf(z) > ZCUT){
        const uint16_t* fb = fB + ((size_t)b * T_ + t) * 640 + w;
        float dot = a0 * bf2f(fb[0]) + a1 * bf2f(fb[128]) + a2 * bf2f(fb[256])
                  + a3 * bf2f(fb[384]) + a4 * bf2f(fb[512]);
        float sil = z / (1.0f + __expf(-z));
        float corr = wi * sil - dot - A0C * wi;
        size_t idx = ((size_t)b * S_ + s) * T_ + t;
        if (OUTBF){
          uint32_t* wp = (uint32_t*)outv + (idx >> 1);
          bool hi = (idx & 1u) != 0;
          uint32_t assumed, old = *wp;
          do {
            assumed = old;
            uint16_t h = hi ? (uint16_t)(assumed >> 16) : (uint16_t)(assumed & 0xFFFFu);
            uint16_t nh = f2bf(bf2f(h) + corr);
            uint32_t nw = hi ? ((assumed & 0x0000FFFFu) | ((uint32_t)nh << 16))
                             : ((assumed & 0xFFFF0000u) | (uint32_t)nh);
            old = atomicCAS(wp, assumed, nw);
          } while (old != assumed);
        } else {
          atomicAdd((float*)outv + idx, corr);
        }
      }
    }
  }
}

extern "C" void kernel_launch(void* const* d_in, const int* in_sizes, int n_in,
                              void* d_out, int out_size, void* d_ws, size_t ws_size,
                              hipStream_t stream){
  char* ws = (char*)d_ws;
  size_t off = 0;
  auto alloc = [&](size_t bytes)->char*{
    char* p = ws + off; off += (bytes + 255) & ~(size_t)255; return p;
  };
  float*    WsT  = (float*)   alloc((size_t)D_*W_*4);
  float*    WtT  = (float*)   alloc((size_t)D_*W_*4);
  float*    wsof = (float*)   alloc(W_*4);
  float*    wtof = (float*)   alloc(W_*4);
  float*    wif  = (float*)   alloc(W_*4);
  float*    cbias= (float*)   alloc(4);
  int*      rowCnt=(int*)     alloc(4);
  uint32_t* rowList=(uint32_t*)alloc((size_t)ROWCAP*4);
  float*    psT  = (float*)   alloc((size_t)B_*S_*W_*4);
  float*    ptT  = (float*)   alloc((size_t)B_*T_*W_*4);
  float*    slin = (float*)   alloc((size_t)B_*S_*4);
  float*    tlin = (float*)   alloc((size_t)B_*T_*4);
  float*    maxT = (float*)   alloc((size_t)B_*W_*4);
  uint16_t* featA= (uint16_t*)alloc((size_t)B_*S_*640*2);
  uint16_t* featB= (uint16_t*)alloc((size_t)B_*T_*640*2);

  // host-side dtype dispatch from byte sizes (fp32 if ambiguous)
  bool inbf  = (in_sizes[0] == (int)((size_t)B_*S_*D_*2));
  bool outbf = (out_size    == (int)((size_t)B_*S_*T_*2));

  if (inbf){
    hipLaunchKernelGGL((prep_k<1>), dim3(32), dim3(256), 0, stream,
        d_in[2], d_in[3], d_in[4], d_in[5], d_in[6], d_in[7],
        WsT, WtT, wsof, wtof, wif, cbias, maxT, rowCnt);
    hipLaunchKernelGGL((proj_k<1,0>), dim3(B_*S_/16), dim3(256), 0, stream,
        d_in[0], WsT, wsof, wif, psT, slin, featA, maxT);
    hipLaunchKernelGGL((proj_k<1,1>), dim3(B_*T_/16), dim3(256), 0, stream,
        d_in[1], WtT, wtof, wif, ptT, tlin, featB, maxT);
  } else {
    hipLaunchKernelGGL((prep_k<0>), dim3(32), dim3(256), 0, stream,
        d_in[2], d_in[3], d_in[4], d_in[5], d_in[6], d_in[7],
        WsT, WtT, wsof, wtof, wif, cbias, maxT, rowCnt);
    hipLaunchKernelGGL((proj_k<0,0>), dim3(B_*S_/16), dim3(256), 0, stream,
        d_in[0], WsT, wsof, wif, psT, slin, featA, maxT);
    hipLaunchKernelGGL((proj_k<0,1>), dim3(B_*T_/16), dim3(256), 0, stream,
        d_in[1], WtT, wtof, wif, ptT, tlin, featB, maxT);
  }
  if (outbf)
    hipLaunchKernelGGL((gemm_k<1>), dim3(T_/128, B_*S_/128), dim3(256), 0, stream,
        featA, featB, slin, tlin, cbias, d_out);
  else
    hipLaunchKernelGGL((gemm_k<0>), dim3(T_/128, B_*S_/128), dim3(256), 0, stream,
        featA, featB, slin, tlin, cbias, d_out);
  hipLaunchKernelGGL(flagrows_k, dim3(W_, B_), dim3(256), 0, stream,
      psT, maxT, rowList, rowCnt);
  if (outbf)
    hipLaunchKernelGGL((fixscan_k<1>), dim3(2048), dim3(256), 0, stream,
        psT, ptT, wif, featA, featB, rowList, rowCnt, d_out);
  else
    hipLaunchKernelGGL((fixscan_k<0>), dim3(2048), dim3(256), 0, stream,
        psT, ptT, wif, featA, featB, rowList, rowCnt, d_out);
}